// Round 27
// baseline (344.187 us; speedup 1.0000x reference)
//
#include <hip/hip_runtime.h>

#define BB 8
#define TT 4096
#define DD 768
#define MM (BB*TT)   // 32768

typedef _Float16 f16;
typedef _Float16 f16x8 __attribute__((ext_vector_type(8)));
typedef float f32x4 __attribute__((ext_vector_type(4)));

typedef __attribute__((address_space(1))) void void_g;
typedef __attribute__((address_space(3))) void void_l;

// async global->LDS, 16B per lane. LDS dest = wave-uniform base + lane*16 (linear).
__device__ __forceinline__ void gload16(const void* g, void* l) {
  __builtin_amdgcn_global_load_lds((void_g*)g, (void_l*)l, 16, 0, 0);
}

// ---------------- fused: mask compaction (blocks 0-7) + e-vector (8-10) ---
// compact: idx[j]->t, nb[b]. evec: e[d] = sum_n bq[n]*Wk[n,d]
// (8 independent accumulator chains -- pipelined loads).
__global__ __launch_bounds__(256)
void compact_evec(const int* __restrict__ mask, int* __restrict__ idx,
                  int* __restrict__ nbv, const float* __restrict__ Wk,
                  const float* __restrict__ bq, float* __restrict__ e) {
  if (blockIdx.x >= 8) {
    const int d = (blockIdx.x - 8) * 256 + threadIdx.x;
    float a0 = 0.f, a1 = 0.f, a2 = 0.f, a3 = 0.f;
    float a4 = 0.f, a5 = 0.f, a6 = 0.f, a7 = 0.f;
    for (int n = 0; n < DD; n += 8) {
      a0 = fmaf(bq[n],     Wk[(size_t)(n)     * DD + d], a0);
      a1 = fmaf(bq[n + 1], Wk[(size_t)(n + 1) * DD + d], a1);
      a2 = fmaf(bq[n + 2], Wk[(size_t)(n + 2) * DD + d], a2);
      a3 = fmaf(bq[n + 3], Wk[(size_t)(n + 3) * DD + d], a3);
      a4 = fmaf(bq[n + 4], Wk[(size_t)(n + 4) * DD + d], a4);
      a5 = fmaf(bq[n + 5], Wk[(size_t)(n + 5) * DD + d], a5);
      a6 = fmaf(bq[n + 6], Wk[(size_t)(n + 6) * DD + d], a6);
      a7 = fmaf(bq[n + 7], Wk[(size_t)(n + 7) * DD + d], a7);
    }
    e[d] = ((a0 + a1) + (a2 + a3)) + ((a4 + a5) + (a6 + a7));
    return;
  }
  __shared__ int wcnt[4];
  const int b = blockIdx.x;
  const int w = threadIdx.x >> 6, l = threadIdx.x & 63;
  const int* mb = mask + b * TT + w * 1024;
  int mv[16];
  unsigned long long bal[16];
#pragma unroll
  for (int c = 0; c < 16; ++c) {
    mv[c] = mb[c * 64 + l];
    bal[c] = __ballot(mv[c] != 0);
  }
  int tot = 0;
#pragma unroll
  for (int c = 0; c < 16; ++c) tot += __popcll(bal[c]);
  if (l == 0) wcnt[w] = tot;
  __syncthreads();
  int base = 0;
  for (int ww = 0; ww < w; ++ww) base += wcnt[ww];
#pragma unroll
  for (int c = 0; c < 16; ++c) {
    const int pre = __popcll(bal[c] & ((1ull << l) - 1ull));
    if (mv[c]) idx[b * TT + base + pre] = w * 1024 + c * 64 + l;
    base += __popcll(bal[c]);
  }
  if (w == 3 && l == 0) nbv[b] = base;
}

// ---------------- fused prep: gather+cvt X (blocks 0-4095) ----------------
//                  + weight transpose-cvt (blocks 4096-4383)
__global__ __launch_bounds__(256)
void prep2(const float* __restrict__ X, const int* __restrict__ idx,
           const int* __restrict__ nbv, const float* __restrict__ e,
           f16* __restrict__ Xc, float* __restrict__ vb,
           const float* __restrict__ Wq, const float* __restrict__ Wk,
           f16* __restrict__ WqT, f16* __restrict__ WkT) {
  __shared__ float tile[64][65];
  if (blockIdx.x >= 4096) {
    const int v = blockIdx.x - 4096;          // 0..287 = (12,12,2)
    const int bx = v % 12, by = (v / 12) % 12, bz = v / 144;
    const float* src = bz ? Wk : Wq;
    f16* dst = bz ? WkT : WqT;
    const int n0 = bx * 64, d0 = by * 64;
    const int r = threadIdx.x >> 6, c = threadIdx.x & 63;
#pragma unroll
    for (int k = 0; k < 16; ++k)
      tile[k * 4 + r][c] = src[(size_t)(n0 + k * 4 + r) * DD + d0 + c];
    __syncthreads();
#pragma unroll
    for (int k = 0; k < 16; ++k)
      dst[(size_t)(d0 + k * 4 + r) * DD + n0 + c] = (f16)tile[c][k * 4 + r];
    return;
  }
  const int rr = blockIdx.x * 8 + (threadIdx.x >> 5);
  const int b = rr >> 12, j = rr & 4095;
  const int l = threadIdx.x & 31;
  if (j >= nbv[b]) return;
  const float scale = 0.036084391824351613f;  // 1/sqrt(768)
  const float* src = X + ((size_t)b * TT + idx[b * TT + j]) * DD + l * 24;
  f16* dst = Xc + ((size_t)b * TT + j) * DD + l * 24;
  const float* ep = e + l * 24;
  float vp = 0.f;
#pragma unroll
  for (int c = 0; c < 3; ++c) {
    float4 a = *(const float4*)(src + c * 8);
    float4 d4 = *(const float4*)(src + c * 8 + 4);
    f16x8 o;
    o[0] = (f16)a.x;  o[1] = (f16)a.y;  o[2] = (f16)a.z;  o[3] = (f16)a.w;
    o[4] = (f16)d4.x; o[5] = (f16)d4.y; o[6] = (f16)d4.z; o[7] = (f16)d4.w;
    *(f16x8*)(dst + c * 8) = o;
    vp += a.x * ep[c * 8]     + a.y * ep[c * 8 + 1] +
          a.z * ep[c * 8 + 2] + a.w * ep[c * 8 + 3] +
          d4.x * ep[c * 8 + 4] + d4.y * ep[c * 8 + 5] +
          d4.z * ep[c * 8 + 6] + d4.w * ep[c * 8 + 7];
  }
#pragma unroll
  for (int off = 1; off < 32; off <<= 1) vp += __shfl_xor(vp, off);
  if (l == 0) vb[b * TT + j] = vp * scale;
}

// ---------------- MT[j][i] = sum_n WkT[j,n] * WqT[i,n]  (= M^T) -----------
__global__ __launch_bounds__(256, 3)
void gemm_mt(const f16* __restrict__ WkT, const f16* __restrict__ WqT,
             f16* __restrict__ MT) {
  __shared__ f16 As[2][64 * 32];
  __shared__ f16 Ws[2][256 * 32];
  const int m0 = blockIdx.x * 64;
  const int n0 = blockIdx.y * 256;
  const int t = threadIdx.x;
  const int lane = t & 63;
  const int w = t >> 6;
  const int wn = w * 64;
  const int fr = lane & 15, fq = lane >> 4;
  const int xrd = ((fr >> 1) & 3) << 3;

  f32x4 acc[4][4] = {};

  const int r0 = t >> 2;
  const int c8 = ((t & 3) ^ ((t >> 3) & 3)) * 8;
  const f16* w0 = WqT + (size_t)(n0 + r0) * DD + c8;
  const f16* a0 = WkT + (size_t)(m0 + r0) * DD + c8;

#define PSTAGE(bf, ks_) do { \
    const int k0_ = (ks_) * 32; \
    gload16(a0 + k0_,                      &As[bf][w * 512]); \
    gload16(w0 + k0_,                      &Ws[bf][w * 512]); \
    gload16(w0 + (size_t)64  * DD + k0_,   &Ws[bf][2048 + w * 512]); \
    gload16(w0 + (size_t)128 * DD + k0_,   &Ws[bf][4096 + w * 512]); \
    gload16(w0 + (size_t)192 * DD + k0_,   &Ws[bf][6144 + w * 512]); \
  } while (0)

  PSTAGE(0, 0);
  __syncthreads();
  for (int ks = 0; ks < 24; ++ks) {
    const int bf = ks & 1;
    if (ks + 1 < 24) PSTAGE(bf ^ 1, ks + 1);
    f16x8 a[4], bfr[4];
#pragma unroll
    for (int i = 0; i < 4; ++i)
      a[i] = *(const f16x8*)&As[bf][(((i * 16 + fr) * 32) + fq * 8) ^ xrd];
#pragma unroll
    for (int j = 0; j < 4; ++j)
      bfr[j] = *(const f16x8*)&Ws[bf][(((wn + j * 16 + fr) * 32) + fq * 8) ^ xrd];
#pragma unroll
    for (int i = 0; i < 4; ++i)
#pragma unroll
      for (int j = 0; j < 4; ++j)
        acc[i][j] = __builtin_amdgcn_mfma_f32_16x16x32_f16(a[i], bfr[j], acc[i][j], 0, 0, 0);
    __syncthreads();
  }
#undef PSTAGE

#pragma unroll
  for (int j = 0; j < 4; ++j) {
    const int col = n0 + wn + j * 16 + fr;
#pragma unroll
    for (int i = 0; i < 4; ++i)
#pragma unroll
      for (int r = 0; r < 4; ++r) {
        const int row = m0 + i * 16 + fq * 4 + r;
        MT[(size_t)row * DD + col] = (f16)acc[i][j][r];
      }
  }
}

// ---------------- projY: Y = Xc * MT^T -> fragment layout -----------------
__global__ __launch_bounds__(256, 3)
void projY(const f16* __restrict__ Xc, const f16* __restrict__ MT,
           const int* __restrict__ nbv, f16* __restrict__ Yf) {
  const int b  = blockIdx.x >> 6;
  const int m0 = (blockIdx.x & 63) * 64;
  const int nb = nbv[b];
  if (m0 >= ((nb + 63) & ~63)) return;

  __shared__ f16 As[2][64 * 32];
  __shared__ f16 Ws[2][256 * 32];
  const int n0 = blockIdx.y * 256;
  const int t = threadIdx.x;
  const int lane = t & 63;
  const int w = t >> 6;
  const int wn = w * 64;
  const int fr = lane & 15, fq = lane >> 4;
  const int xrd = ((fr >> 1) & 3) << 3;

  f32x4 acc[4][4] = {};

  const int r0 = t >> 2;
  const int c8 = ((t & 3) ^ ((t >> 3) & 3)) * 8;
  const f16* w0 = MT + (size_t)(n0 + r0) * DD + c8;
  const f16* a0 = Xc + (size_t)b * TT * DD + (size_t)(m0 + r0) * DD + c8;

#define PSTAGE(bf, ks_) do { \
    const int k0_ = (ks_) * 32; \
    gload16(a0 + k0_,                      &As[bf][w * 512]); \
    gload16(w0 + k0_,                      &Ws[bf][w * 512]); \
    gload16(w0 + (size_t)64  * DD + k0_,   &Ws[bf][2048 + w * 512]); \
    gload16(w0 + (size_t)128 * DD + k0_,   &Ws[bf][4096 + w * 512]); \
    gload16(w0 + (size_t)192 * DD + k0_,   &Ws[bf][6144 + w * 512]); \
  } while (0)

  PSTAGE(0, 0);
  __syncthreads();
  for (int ks = 0; ks < 24; ++ks) {
    const int bf = ks & 1;
    if (ks + 1 < 24) PSTAGE(bf ^ 1, ks + 1);
    f16x8 a[4], bfr[4];
#pragma unroll
    for (int i = 0; i < 4; ++i)
      a[i] = *(const f16x8*)&As[bf][(((i * 16 + fr) * 32) + fq * 8) ^ xrd];
#pragma unroll
    for (int j = 0; j < 4; ++j)
      bfr[j] = *(const f16x8*)&Ws[bf][(((wn + j * 16 + fr) * 32) + fq * 8) ^ xrd];
#pragma unroll
    for (int i = 0; i < 4; ++i)
#pragma unroll
      for (int j = 0; j < 4; ++j)
        acc[i][j] = __builtin_amdgcn_mfma_f32_16x16x32_f16(a[i], bfr[j], acc[i][j], 0, 0, 0);
    __syncthreads();
  }
#undef PSTAGE

#pragma unroll
  for (int j = 0; j < 4; ++j) {
    const int col = n0 + wn + j * 16 + fr;
#pragma unroll
    for (int i = 0; i < 4; ++i) {
#pragma unroll
      for (int r = 0; r < 4; ++r) {
        const int rowc = m0 + i * 16 + fq * 4 + r;
        const size_t q = (size_t)b * TT * DD +
            ((((size_t)(rowc >> 6) * 24 + (col >> 5)) * 4 + ((rowc >> 4) & 3)) * 512 +
             ((rowc & 15) + (((col >> 3) & 3) << 4)) * 8 + (col & 7));
        Yf[q] = (f16)acc[i][j][r];
      }
    }
  }
}

// ---------------- attn17c: compacted QK^T row-stats (proven) --------------
__global__ __launch_bounds__(256, 3)
void attn17c(const f16* __restrict__ Qf, const f16* __restrict__ K,
             const float* __restrict__ vbias, const int* __restrict__ nbv,
             float* __restrict__ pzv, float* __restrict__ sdg) {
  const int bid = blockIdx.x;
  const int qs = bid / 48;
  const int rem = bid % 48;
  const int kh = rem >> 3;
  const int bb = rem & 7;
  const int nb = nbv[bb];
  if (qs * 128 >= nb) return;

  __shared__ f16 Ks[2][128 * 64];
  const int t = threadIdx.x, l = t & 63, w = t >> 6;
  const int wq = w >> 1, wk = w & 1;
  const int fr = l & 15, fq = l >> 4;
  const int q0 = qs * 128;
  const float scale = 0.036084391824351613f;  // 1/sqrt(768)
  const int nkt = (nb + 127) >> 7;
  const int q6 = nkt / 6, r6 = nkt % 6;
  const int cnt = q6 + (kh < r6 ? 1 : 0);
  const int lo  = kh * q6 + (kh < r6 ? kh : r6);
  const int P = cnt * 12;

  const f16* Kg = K + (size_t)bb * TT * DD;
  const f16* qf = Qf + (size_t)bb * TT * DD + (size_t)(qs * 2 + wq) * 49152 + (size_t)l * 8;
  const float* vbp = vbias + bb * TT;

  const int c8 = ((t & 3) ^ ((t >> 3) & 3)) * 8;
  const f16* klo = Kg + (size_t)(t >> 2) * DD + c8;
  const f16* khi = klo + (size_t)64 * DD;

  const int sx = (fq ^ ((fr >> 1) & 3)) * 8;
  const int bbase = (wk * 64 + fr) * 32 + sx;

  // prologue vb loads: all kts this block will touch (cnt <= 3)
  const int bfr0 = wk * 64 + fr;
  const int k0c = (lo + 0) * 128 + bfr0;
  const int k1c = (lo + (cnt > 1 ? 1 : 0)) * 128 + bfr0;
  const int k2c = (lo + (cnt > 2 ? 2 : 0)) * 128 + bfr0;
  const float v00 = vbp[k0c], v01 = vbp[k0c + 16], v02 = vbp[k0c + 32], v03 = vbp[k0c + 48];
  const float v10 = vbp[k1c], v11 = vbp[k1c + 16], v12 = vbp[k1c + 32], v13 = vbp[k1c + 48];
  const float v20 = vbp[k2c], v21 = vbp[k2c + 16], v22 = vbp[k2c + 32], v23 = vbp[k2c + 48];

  f32x4 acc[4][4] = {};
  f32x4 zacc[4] = {};
  int im0 = 0, im1 = 0, im2 = 0, im3 = 0;
  float vb0 = 0.f, vb1 = 0.f, vb2 = 0.f, vb3 = 0.f;
  f16x8 avA[4], avB[4];

#define STAGE(bf, p_) do { \
    const size_t o0 = (size_t)(lo + (p_) / 12) * 128 * DD + (size_t)(((p_) % 12) * 64); \
    gload16(klo + o0,      &Ks[bf][w * 512]); \
    gload16(khi + o0,      &Ks[bf][2048 + w * 512]); \
    gload16(klo + o0 + 32, &Ks[bf][4096 + w * 512]); \
    gload16(khi + o0 + 32, &Ks[bf][6144 + w * 512]); \
  } while (0)

#define QLOAD(dst, dc_) do { \
    const f16* qp_ = qf + (size_t)(dc_) * 2048; \
    _Pragma("unroll") \
    for (int i = 0; i < 4; ++i) (dst)[i] = *(const f16x8*)(qp_ + i * 512); \
  } while (0)

#define MFMA_ALL(av_, bufv, off_) do { \
    f16x8 bv[4]; \
    _Pragma("unroll") \
    for (int j = 0; j < 4; ++j) bv[j] = *(const f16x8*)&Ks[bufv][(off_) + bbase + j * 512]; \
    __builtin_amdgcn_s_setprio(1); \
    _Pragma("unroll") \
    for (int i = 0; i < 4; ++i) \
      _Pragma("unroll") \
      for (int j = 0; j < 4; ++j) \
        acc[i][j] = __builtin_amdgcn_mfma_f32_16x16x32_f16((av_)[i], bv[j], acc[i][j], 0, 0, 0); \
    __builtin_amdgcn_s_setprio(0); \
  } while (0)

#define KT_EPILOGUE(kt_) do { \
    const float mb0 = im0 ? vb0 : -1e30f; \
    const float mb1 = im1 ? vb1 : -1e30f; \
    const float mb2 = im2 ? vb2 : -1e30f; \
    const float mb3 = im3 ? vb3 : -1e30f; \
    const bool isdiag = ((kt_) == qs); \
    _Pragma("unroll") \
    for (int i = 0; i < 4; ++i) { \
      _Pragma("unroll") \
      for (int rg = 0; rg < 4; ++rg) { \
        float v0 = fmaf(acc[i][0][rg], scale, mb0); \
        float v1 = fmaf(acc[i][1][rg], scale, mb1); \
        float v2 = fmaf(acc[i][2][rg], scale, mb2); \
        float v3 = fmaf(acc[i][3][rg], scale, mb3); \
        if (isdiag) { \
          const int rl = wq * 64 + i * 16 + fq * 4 + rg; \
          const int cl = wk * 64 + fr; \
          if (cl      == rl) sdg[(size_t)bb * TT + q0 + rl] = v0; \
          if (cl + 16 == rl) sdg[(size_t)bb * TT + q0 + rl] = v1; \
          if (cl + 32 == rl) sdg[(size_t)bb * TT + q0 + rl] = v2; \
          if (cl + 48 == rl) sdg[(size_t)bb * TT + q0 + rl] = v3; \
        } \
        zacc[i][rg] += __expf(v0) + __expf(v1) + __expf(v2) + __expf(v3); \
      } \
    } \
    _Pragma("unroll") \
    for (int i = 0; i < 4; ++i) \
      _Pragma("unroll") \
      for (int j = 0; j < 4; ++j) acc[i][j] = (f32x4)(0.f); \
  } while (0)

  STAGE(0, 0);
  QLOAD(avA, 0);
  __syncthreads();

  for (int p = 0; p < P; ++p) {
    const int buf = p & 1;
    const int kt = lo + p / 12, c = p % 12;
    if (c == 0) {  // validity + vb select (register-only)
      const int cb0 = kt * 128 + wk * 64 + fr;
      im0 = (cb0 < nb); im1 = (cb0 + 16 < nb);
      im2 = (cb0 + 32 < nb); im3 = (cb0 + 48 < nb);
      const int q = p / 12;
      if (q == 0)      { vb0 = v00; vb1 = v01; vb2 = v02; vb3 = v03; }
      else if (q == 1) { vb0 = v10; vb1 = v11; vb2 = v12; vb3 = v13; }
      else             { vb0 = v20; vb1 = v21; vb2 = v22; vb3 = v23; }
    }

    QLOAD(avB, 2 * c + 1);
    if (p + 1 < P) STAGE(buf ^ 1, p + 1);
    MFMA_ALL(avA, buf, 0);

    if (p + 1 < P) QLOAD(avA, 2 * (((p + 1) % 12)));
    MFMA_ALL(avB, buf, 4096);

    if (c == 11) KT_EPILOGUE(kt);

    __syncthreads();
  }
#undef STAGE
#undef QLOAD
#undef MFMA_ALL
#undef KT_EPILOGUE

  const int slot = kh * 2 + wk;     // 12 slots
#pragma unroll
  for (int i = 0; i < 4; ++i) {
#pragma unroll
    for (int rg = 0; rg < 4; ++rg) {
      float z = zacc[i][rg];
#pragma unroll
      for (int off = 1; off < 16; off <<= 1) z += __shfl_xor(z, off);
      if (fr == 0) {
        const int row = wq * 64 + i * 16 + fq * 4 + rg;
        pzv[(size_t)slot * MM + bb * TT + q0 + row] = z;
      }
    }
  }
}

// ---------------- fused tail: wdiag inline + gemv, no atomics -------------
// grid (8,3): out[b, y*256+tid] = sum_j Xc[b,j,d] * (exp(sdg[j])/Z[j]).
// wsm computed per 256-chunk from the 12 pz slots (3x redundant, trivial).
__global__ __launch_bounds__(256)
void gemv_final(const f16* __restrict__ Xc, const float* __restrict__ pz,
                const float* __restrict__ sdg, const int* __restrict__ nbv,
                float* __restrict__ out) {
  __shared__ float wsm[256];
  const int b = blockIdx.x;
  const int d = blockIdx.y * 256 + threadIdx.x;
  const int nb = nbv[b];
  float acc = 0.f;
  for (int tb = 0; tb < nb; tb += 256) {
    __syncthreads();
    float wv = 0.f;
    if (tb + (int)threadIdx.x < nb) {
      const int i = b * TT + tb + threadIdx.x;
      float Z = 0.f;
#pragma unroll
      for (int s = 0; s < 12; ++s) Z += pz[(size_t)s * MM + i];
      wv = __expf(sdg[i]) / Z;
    }
    wsm[threadIdx.x] = wv;
    __syncthreads();
    const f16* xp = Xc + ((size_t)b * TT + tb) * DD + d;
    const int lim = (nb - tb < 256) ? (nb - tb) : 256;
#pragma unroll 4
    for (int k = 0; k < lim; ++k) acc += (float)xp[(size_t)k * DD] * wsm[k];
  }
  out[b * DD + d] = acc;
}

extern "C" void kernel_launch(void* const* d_in, const int* in_sizes, int n_in,
                              void* d_out, int out_size, void* d_ws, size_t ws_size,
                              hipStream_t stream) {
  const float* X    = (const float*)d_in[0];
  const int*   mask = (const int*)d_in[1];
  const float* Wq_w = (const float*)d_in[2];
  const float* Wq_b = (const float*)d_in[3];
  const float* Wk_w = (const float*)d_in[4];
  const float* Wk_b = (const float*)d_in[5];
  float* out = (float*)d_out;
  (void)Wk_b;   // cancels in row-softmax (u[i], c terms)

  const size_t n2 = (size_t)MM * DD;      // 25.17M f16 elems
  const size_t wde = (size_t)DD * DD;

  // workspace layout (~106 MB)
  char* p = (char*)d_ws;
  f16* Yf  = (f16*)p;           p += n2 * sizeof(f16);
  f16* Xc  = (f16*)p;           p += n2 * sizeof(f16);
  f16* WqT = (f16*)p;           p += wde * sizeof(f16);
  f16* WkT = (f16*)p;           p += wde * sizeof(f16);
  f16* MT  = (f16*)p;           p += wde * sizeof(f16);
  float* ev = (float*)p;        p += DD * sizeof(float);
  int* idx = (int*)p;           p += (size_t)MM * sizeof(int);
  int* nbv = (int*)p;           p += 64;
  float* vb = (float*)p;        p += (size_t)MM * sizeof(float);
  float* pz = (float*)p;        p += (size_t)12 * MM * sizeof(float);
  float* sdg = (float*)p;       p += (size_t)MM * sizeof(float);

  compact_evec<<<11, 256, 0, stream>>>(mask, idx, nbv, Wk_w, Wq_b, ev);
  prep2<<<4384, 256, 0, stream>>>(X, idx, nbv, ev, Xc, vb,
                                  Wq_w, Wk_w, WqT, WkT);
  gemm_mt<<<dim3(12, 3), 256, 0, stream>>>(WkT, WqT, MT);
  projY<<<dim3(512, 3), 256, 0, stream>>>(Xc, MT, nbv, Yf);
  attn17c<<<1536, 256, 0, stream>>>(Yf, Xc, vb, nbv, pz, sdg);
  gemv_final<<<dim3(8, 3), 256, 0, stream>>>(Xc, pz, sdg, nbv, out);
}

// Round 28
// 238.114 us; speedup vs baseline: 1.4455x; 1.4455x over previous
//
#include <hip/hip_runtime.h>

#define BB 8
#define TT 4096
#define DD 768
#define MM (BB*TT)   // 32768

typedef _Float16 f16;
typedef _Float16 f16x8 __attribute__((ext_vector_type(8)));
typedef float f32x4 __attribute__((ext_vector_type(4)));

typedef __attribute__((address_space(1))) void void_g;
typedef __attribute__((address_space(3))) void void_l;

// async global->LDS, 16B per lane. LDS dest = wave-uniform base + lane*16 (linear).
__device__ __forceinline__ void gload16(const void* g, void* l) {
  __builtin_amdgcn_global_load_lds((void_g*)g, (void_l*)l, 16, 0, 0);
}

// ---------------- fused: mask compaction (blocks 0-7) + e-vector (8-10) ---
// compact: idx[j]->t, nb[b]. evec: e[d] = sum_n bq[n]*Wk[n,d]
// (8 independent accumulator chains -- pipelined loads).
__global__ __launch_bounds__(256)
void compact_evec(const int* __restrict__ mask, int* __restrict__ idx,
                  int* __restrict__ nbv, const float* __restrict__ Wk,
                  const float* __restrict__ bq, float* __restrict__ e) {
  if (blockIdx.x >= 8) {
    const int d = (blockIdx.x - 8) * 256 + threadIdx.x;
    float a0 = 0.f, a1 = 0.f, a2 = 0.f, a3 = 0.f;
    float a4 = 0.f, a5 = 0.f, a6 = 0.f, a7 = 0.f;
    for (int n = 0; n < DD; n += 8) {
      a0 = fmaf(bq[n],     Wk[(size_t)(n)     * DD + d], a0);
      a1 = fmaf(bq[n + 1], Wk[(size_t)(n + 1) * DD + d], a1);
      a2 = fmaf(bq[n + 2], Wk[(size_t)(n + 2) * DD + d], a2);
      a3 = fmaf(bq[n + 3], Wk[(size_t)(n + 3) * DD + d], a3);
      a4 = fmaf(bq[n + 4], Wk[(size_t)(n + 4) * DD + d], a4);
      a5 = fmaf(bq[n + 5], Wk[(size_t)(n + 5) * DD + d], a5);
      a6 = fmaf(bq[n + 6], Wk[(size_t)(n + 6) * DD + d], a6);
      a7 = fmaf(bq[n + 7], Wk[(size_t)(n + 7) * DD + d], a7);
    }
    e[d] = ((a0 + a1) + (a2 + a3)) + ((a4 + a5) + (a6 + a7));
    return;
  }
  __shared__ int wcnt[4];
  const int b = blockIdx.x;
  const int w = threadIdx.x >> 6, l = threadIdx.x & 63;
  const int* mb = mask + b * TT + w * 1024;
  int mv[16];
  unsigned long long bal[16];
#pragma unroll
  for (int c = 0; c < 16; ++c) {
    mv[c] = mb[c * 64 + l];
    bal[c] = __ballot(mv[c] != 0);
  }
  int tot = 0;
#pragma unroll
  for (int c = 0; c < 16; ++c) tot += __popcll(bal[c]);
  if (l == 0) wcnt[w] = tot;
  __syncthreads();
  int base = 0;
  for (int ww = 0; ww < w; ++ww) base += wcnt[ww];
#pragma unroll
  for (int c = 0; c < 16; ++c) {
    const int pre = __popcll(bal[c] & ((1ull << l) - 1ull));
    if (mv[c]) idx[b * TT + base + pre] = w * 1024 + c * 64 + l;
    base += __popcll(bal[c]);
  }
  if (w == 3 && l == 0) nbv[b] = base;
}

// ---------------- fused prep: gather+cvt X (blocks 0-4095) ----------------
//                  + weight transpose-cvt (blocks 4096-4383)
__global__ __launch_bounds__(256)
void prep2(const float* __restrict__ X, const int* __restrict__ idx,
           const int* __restrict__ nbv, const float* __restrict__ e,
           f16* __restrict__ Xc, float* __restrict__ vb,
           const float* __restrict__ Wq, const float* __restrict__ Wk,
           f16* __restrict__ WqT, f16* __restrict__ WkT) {
  __shared__ float tile[64][65];
  if (blockIdx.x >= 4096) {
    const int v = blockIdx.x - 4096;          // 0..287 = (12,12,2)
    const int bx = v % 12, by = (v / 12) % 12, bz = v / 144;
    const float* src = bz ? Wk : Wq;
    f16* dst = bz ? WkT : WqT;
    const int n0 = bx * 64, d0 = by * 64;
    const int r = threadIdx.x >> 6, c = threadIdx.x & 63;
#pragma unroll
    for (int k = 0; k < 16; ++k)
      tile[k * 4 + r][c] = src[(size_t)(n0 + k * 4 + r) * DD + d0 + c];
    __syncthreads();
#pragma unroll
    for (int k = 0; k < 16; ++k)
      dst[(size_t)(d0 + k * 4 + r) * DD + n0 + c] = (f16)tile[c][k * 4 + r];
    return;
  }
  const int rr = blockIdx.x * 8 + (threadIdx.x >> 5);
  const int b = rr >> 12, j = rr & 4095;
  const int l = threadIdx.x & 31;
  if (j >= nbv[b]) return;
  const float scale = 0.036084391824351613f;  // 1/sqrt(768)
  const float* src = X + ((size_t)b * TT + idx[b * TT + j]) * DD + l * 24;
  f16* dst = Xc + ((size_t)b * TT + j) * DD + l * 24;
  const float* ep = e + l * 24;
  float vp = 0.f;
#pragma unroll
  for (int c = 0; c < 3; ++c) {
    float4 a = *(const float4*)(src + c * 8);
    float4 d4 = *(const float4*)(src + c * 8 + 4);
    f16x8 o;
    o[0] = (f16)a.x;  o[1] = (f16)a.y;  o[2] = (f16)a.z;  o[3] = (f16)a.w;
    o[4] = (f16)d4.x; o[5] = (f16)d4.y; o[6] = (f16)d4.z; o[7] = (f16)d4.w;
    *(f16x8*)(dst + c * 8) = o;
    vp += a.x * ep[c * 8]     + a.y * ep[c * 8 + 1] +
          a.z * ep[c * 8 + 2] + a.w * ep[c * 8 + 3] +
          d4.x * ep[c * 8 + 4] + d4.y * ep[c * 8 + 5] +
          d4.z * ep[c * 8 + 6] + d4.w * ep[c * 8 + 7];
  }
#pragma unroll
  for (int off = 1; off < 32; off <<= 1) vp += __shfl_xor(vp, off);
  if (l == 0) vb[b * TT + j] = vp * scale;
}

// ---------------- MT[j][i] = sum_n WkT[j,n] * WqT[i,n]  (= M^T) -----------
__global__ __launch_bounds__(256, 3)
void gemm_mt(const f16* __restrict__ WkT, const f16* __restrict__ WqT,
             f16* __restrict__ MT) {
  __shared__ f16 As[2][64 * 32];
  __shared__ f16 Ws[2][256 * 32];
  const int m0 = blockIdx.x * 64;
  const int n0 = blockIdx.y * 256;
  const int t = threadIdx.x;
  const int lane = t & 63;
  const int w = t >> 6;
  const int wn = w * 64;
  const int fr = lane & 15, fq = lane >> 4;
  const int xrd = ((fr >> 1) & 3) << 3;

  f32x4 acc[4][4] = {};

  const int r0 = t >> 2;
  const int c8 = ((t & 3) ^ ((t >> 3) & 3)) * 8;
  const f16* w0 = WqT + (size_t)(n0 + r0) * DD + c8;
  const f16* a0 = WkT + (size_t)(m0 + r0) * DD + c8;

#define PSTAGE(bf, ks_) do { \
    const int k0_ = (ks_) * 32; \
    gload16(a0 + k0_,                      &As[bf][w * 512]); \
    gload16(w0 + k0_,                      &Ws[bf][w * 512]); \
    gload16(w0 + (size_t)64  * DD + k0_,   &Ws[bf][2048 + w * 512]); \
    gload16(w0 + (size_t)128 * DD + k0_,   &Ws[bf][4096 + w * 512]); \
    gload16(w0 + (size_t)192 * DD + k0_,   &Ws[bf][6144 + w * 512]); \
  } while (0)

  PSTAGE(0, 0);
  __syncthreads();
  for (int ks = 0; ks < 24; ++ks) {
    const int bf = ks & 1;
    if (ks + 1 < 24) PSTAGE(bf ^ 1, ks + 1);
    f16x8 a[4], bfr[4];
#pragma unroll
    for (int i = 0; i < 4; ++i)
      a[i] = *(const f16x8*)&As[bf][(((i * 16 + fr) * 32) + fq * 8) ^ xrd];
#pragma unroll
    for (int j = 0; j < 4; ++j)
      bfr[j] = *(const f16x8*)&Ws[bf][(((wn + j * 16 + fr) * 32) + fq * 8) ^ xrd];
#pragma unroll
    for (int i = 0; i < 4; ++i)
#pragma unroll
      for (int j = 0; j < 4; ++j)
        acc[i][j] = __builtin_amdgcn_mfma_f32_16x16x32_f16(a[i], bfr[j], acc[i][j], 0, 0, 0);
    __syncthreads();
  }
#undef PSTAGE

#pragma unroll
  for (int j = 0; j < 4; ++j) {
    const int col = n0 + wn + j * 16 + fr;
#pragma unroll
    for (int i = 0; i < 4; ++i)
#pragma unroll
      for (int r = 0; r < 4; ++r) {
        const int row = m0 + i * 16 + fq * 4 + r;
        MT[(size_t)row * DD + col] = (f16)acc[i][j][r];
      }
  }
}

// ---------------- projY: Y = Xc * MT^T -> fragment layout -----------------
__global__ __launch_bounds__(256, 3)
void projY(const f16* __restrict__ Xc, const f16* __restrict__ MT,
           const int* __restrict__ nbv, f16* __restrict__ Yf) {
  const int b  = blockIdx.x >> 6;
  const int m0 = (blockIdx.x & 63) * 64;
  const int nb = nbv[b];
  if (m0 >= ((nb + 63) & ~63)) return;

  __shared__ f16 As[2][64 * 32];
  __shared__ f16 Ws[2][256 * 32];
  const int n0 = blockIdx.y * 256;
  const int t = threadIdx.x;
  const int lane = t & 63;
  const int w = t >> 6;
  const int wn = w * 64;
  const int fr = lane & 15, fq = lane >> 4;
  const int xrd = ((fr >> 1) & 3) << 3;

  f32x4 acc[4][4] = {};

  const int r0 = t >> 2;
  const int c8 = ((t & 3) ^ ((t >> 3) & 3)) * 8;
  const f16* w0 = MT + (size_t)(n0 + r0) * DD + c8;
  const f16* a0 = Xc + (size_t)b * TT * DD + (size_t)(m0 + r0) * DD + c8;

#define PSTAGE(bf, ks_) do { \
    const int k0_ = (ks_) * 32; \
    gload16(a0 + k0_,                      &As[bf][w * 512]); \
    gload16(w0 + k0_,                      &Ws[bf][w * 512]); \
    gload16(w0 + (size_t)64  * DD + k0_,   &Ws[bf][2048 + w * 512]); \
    gload16(w0 + (size_t)128 * DD + k0_,   &Ws[bf][4096 + w * 512]); \
    gload16(w0 + (size_t)192 * DD + k0_,   &Ws[bf][6144 + w * 512]); \
  } while (0)

  PSTAGE(0, 0);
  __syncthreads();
  for (int ks = 0; ks < 24; ++ks) {
    const int bf = ks & 1;
    if (ks + 1 < 24) PSTAGE(bf ^ 1, ks + 1);
    f16x8 a[4], bfr[4];
#pragma unroll
    for (int i = 0; i < 4; ++i)
      a[i] = *(const f16x8*)&As[bf][(((i * 16 + fr) * 32) + fq * 8) ^ xrd];
#pragma unroll
    for (int j = 0; j < 4; ++j)
      bfr[j] = *(const f16x8*)&Ws[bf][(((wn + j * 16 + fr) * 32) + fq * 8) ^ xrd];
#pragma unroll
    for (int i = 0; i < 4; ++i)
#pragma unroll
      for (int j = 0; j < 4; ++j)
        acc[i][j] = __builtin_amdgcn_mfma_f32_16x16x32_f16(a[i], bfr[j], acc[i][j], 0, 0, 0);
    __syncthreads();
  }
#undef PSTAGE

#pragma unroll
  for (int j = 0; j < 4; ++j) {
    const int col = n0 + wn + j * 16 + fr;
#pragma unroll
    for (int i = 0; i < 4; ++i) {
#pragma unroll
      for (int r = 0; r < 4; ++r) {
        const int rowc = m0 + i * 16 + fq * 4 + r;
        const size_t q = (size_t)b * TT * DD +
            ((((size_t)(rowc >> 6) * 24 + (col >> 5)) * 4 + ((rowc >> 4) & 3)) * 512 +
             ((rowc & 15) + (((col >> 3) & 3) << 4)) * 8 + (col & 7));
        Yf[q] = (f16)acc[i][j][r];
      }
    }
  }
}

// ---------------- attn17c: compacted QK^T row-stats (proven) --------------
__global__ __launch_bounds__(256, 3)
void attn17c(const f16* __restrict__ Qf, const f16* __restrict__ K,
             const float* __restrict__ vbias, const int* __restrict__ nbv,
             float* __restrict__ pzv, float* __restrict__ sdg) {
  const int bid = blockIdx.x;
  const int qs = bid / 48;
  const int rem = bid % 48;
  const int kh = rem >> 3;
  const int bb = rem & 7;
  const int nb = nbv[bb];
  if (qs * 128 >= nb) return;

  __shared__ f16 Ks[2][128 * 64];
  const int t = threadIdx.x, l = t & 63, w = t >> 6;
  const int wq = w >> 1, wk = w & 1;
  const int fr = l & 15, fq = l >> 4;
  const int q0 = qs * 128;
  const float scale = 0.036084391824351613f;  // 1/sqrt(768)
  const int nkt = (nb + 127) >> 7;
  const int q6 = nkt / 6, r6 = nkt % 6;
  const int cnt = q6 + (kh < r6 ? 1 : 0);
  const int lo  = kh * q6 + (kh < r6 ? kh : r6);
  const int P = cnt * 12;

  const f16* Kg = K + (size_t)bb * TT * DD;
  const f16* qf = Qf + (size_t)bb * TT * DD + (size_t)(qs * 2 + wq) * 49152 + (size_t)l * 8;
  const float* vbp = vbias + bb * TT;

  const int c8 = ((t & 3) ^ ((t >> 3) & 3)) * 8;
  const f16* klo = Kg + (size_t)(t >> 2) * DD + c8;
  const f16* khi = klo + (size_t)64 * DD;

  const int sx = (fq ^ ((fr >> 1) & 3)) * 8;
  const int bbase = (wk * 64 + fr) * 32 + sx;

  // prologue vb loads: all kts this block will touch (cnt <= 3)
  const int bfr0 = wk * 64 + fr;
  const int k0c = (lo + 0) * 128 + bfr0;
  const int k1c = (lo + (cnt > 1 ? 1 : 0)) * 128 + bfr0;
  const int k2c = (lo + (cnt > 2 ? 2 : 0)) * 128 + bfr0;
  const float v00 = vbp[k0c], v01 = vbp[k0c + 16], v02 = vbp[k0c + 32], v03 = vbp[k0c + 48];
  const float v10 = vbp[k1c], v11 = vbp[k1c + 16], v12 = vbp[k1c + 32], v13 = vbp[k1c + 48];
  const float v20 = vbp[k2c], v21 = vbp[k2c + 16], v22 = vbp[k2c + 32], v23 = vbp[k2c + 48];

  f32x4 acc[4][4] = {};
  f32x4 zacc[4] = {};
  int im0 = 0, im1 = 0, im2 = 0, im3 = 0;
  float vb0 = 0.f, vb1 = 0.f, vb2 = 0.f, vb3 = 0.f;
  f16x8 avA[4], avB[4];

#define STAGE(bf, p_) do { \
    const size_t o0 = (size_t)(lo + (p_) / 12) * 128 * DD + (size_t)(((p_) % 12) * 64); \
    gload16(klo + o0,      &Ks[bf][w * 512]); \
    gload16(khi + o0,      &Ks[bf][2048 + w * 512]); \
    gload16(klo + o0 + 32, &Ks[bf][4096 + w * 512]); \
    gload16(khi + o0 + 32, &Ks[bf][6144 + w * 512]); \
  } while (0)

#define QLOAD(dst, dc_) do { \
    const f16* qp_ = qf + (size_t)(dc_) * 2048; \
    _Pragma("unroll") \
    for (int i = 0; i < 4; ++i) (dst)[i] = *(const f16x8*)(qp_ + i * 512); \
  } while (0)

#define MFMA_ALL(av_, bufv, off_) do { \
    f16x8 bv[4]; \
    _Pragma("unroll") \
    for (int j = 0; j < 4; ++j) bv[j] = *(const f16x8*)&Ks[bufv][(off_) + bbase + j * 512]; \
    __builtin_amdgcn_s_setprio(1); \
    _Pragma("unroll") \
    for (int i = 0; i < 4; ++i) \
      _Pragma("unroll") \
      for (int j = 0; j < 4; ++j) \
        acc[i][j] = __builtin_amdgcn_mfma_f32_16x16x32_f16((av_)[i], bv[j], acc[i][j], 0, 0, 0); \
    __builtin_amdgcn_s_setprio(0); \
  } while (0)

#define KT_EPILOGUE(kt_) do { \
    const float mb0 = im0 ? vb0 : -1e30f; \
    const float mb1 = im1 ? vb1 : -1e30f; \
    const float mb2 = im2 ? vb2 : -1e30f; \
    const float mb3 = im3 ? vb3 : -1e30f; \
    const bool isdiag = ((kt_) == qs); \
    _Pragma("unroll") \
    for (int i = 0; i < 4; ++i) { \
      _Pragma("unroll") \
      for (int rg = 0; rg < 4; ++rg) { \
        float v0 = fmaf(acc[i][0][rg], scale, mb0); \
        float v1 = fmaf(acc[i][1][rg], scale, mb1); \
        float v2 = fmaf(acc[i][2][rg], scale, mb2); \
        float v3 = fmaf(acc[i][3][rg], scale, mb3); \
        if (isdiag) { \
          const int rl = wq * 64 + i * 16 + fq * 4 + rg; \
          const int cl = wk * 64 + fr; \
          if (cl      == rl) sdg[(size_t)bb * TT + q0 + rl] = v0; \
          if (cl + 16 == rl) sdg[(size_t)bb * TT + q0 + rl] = v1; \
          if (cl + 32 == rl) sdg[(size_t)bb * TT + q0 + rl] = v2; \
          if (cl + 48 == rl) sdg[(size_t)bb * TT + q0 + rl] = v3; \
        } \
        zacc[i][rg] += __expf(v0) + __expf(v1) + __expf(v2) + __expf(v3); \
      } \
    } \
    _Pragma("unroll") \
    for (int i = 0; i < 4; ++i) \
      _Pragma("unroll") \
      for (int j = 0; j < 4; ++j) acc[i][j] = (f32x4)(0.f); \
  } while (0)

  STAGE(0, 0);
  QLOAD(avA, 0);
  __syncthreads();

  for (int p = 0; p < P; ++p) {
    const int buf = p & 1;
    const int kt = lo + p / 12, c = p % 12;
    if (c == 0) {  // validity + vb select (register-only)
      const int cb0 = kt * 128 + wk * 64 + fr;
      im0 = (cb0 < nb); im1 = (cb0 + 16 < nb);
      im2 = (cb0 + 32 < nb); im3 = (cb0 + 48 < nb);
      const int q = p / 12;
      if (q == 0)      { vb0 = v00; vb1 = v01; vb2 = v02; vb3 = v03; }
      else if (q == 1) { vb0 = v10; vb1 = v11; vb2 = v12; vb3 = v13; }
      else             { vb0 = v20; vb1 = v21; vb2 = v22; vb3 = v23; }
    }

    QLOAD(avB, 2 * c + 1);
    if (p + 1 < P) STAGE(buf ^ 1, p + 1);
    MFMA_ALL(avA, buf, 0);

    if (p + 1 < P) QLOAD(avA, 2 * (((p + 1) % 12)));
    MFMA_ALL(avB, buf, 4096);

    if (c == 11) KT_EPILOGUE(kt);

    __syncthreads();
  }
#undef STAGE
#undef QLOAD
#undef MFMA_ALL
#undef KT_EPILOGUE

  const int slot = kh * 2 + wk;     // 12 slots
#pragma unroll
  for (int i = 0; i < 4; ++i) {
#pragma unroll
    for (int rg = 0; rg < 4; ++rg) {
      float z = zacc[i][rg];
#pragma unroll
      for (int off = 1; off < 16; off <<= 1) z += __shfl_xor(z, off);
      if (fr == 0) {
        const int row = wq * 64 + i * 16 + fq * 4 + rg;
        pzv[(size_t)slot * MM + bb * TT + q0 + row] = z;
      }
    }
  }
}

// ---------------- merge 12 partials -> compacted wdiag, zero out ----------
__global__ void merge12c(const float* __restrict__ pz, const float* __restrict__ sdg,
                         const int* __restrict__ nbv,
                         float* __restrict__ wdiagc, float* __restrict__ out) {
  int i = blockIdx.x * 256 + threadIdx.x;
  if (i < BB * DD) out[i] = 0.f;
  if (i >= MM) return;
  const int b = i >> 12, j = i & 4095;
  if (j >= nbv[b]) { wdiagc[i] = 0.f; return; }
  float Z = 0.f;
#pragma unroll
  for (int s = 0; s < 12; ++s) Z += pz[(size_t)s * MM + i];
  wdiagc[i] = __expf(sdg[i]) / Z;
}

// ---------------- compacted gemv: out[b,d] = sum_j Xc[b,j,d]*wdiagc[b,j] --
__global__ __launch_bounds__(256)
void out_gemv_c(const f16* __restrict__ Xc, const float* __restrict__ wdiagc,
                const int* __restrict__ nbv, float* __restrict__ out) {
  __shared__ float wsm[256];
  const int b = blockIdx.z;
  const int nb = nbv[b];
  const int tbase = blockIdx.x * 256;
  if (tbase >= nb) return;
  const int d = blockIdx.y * 256 + threadIdx.x;
  wsm[threadIdx.x] = (tbase + threadIdx.x < nb) ? wdiagc[b * TT + tbase + threadIdx.x] : 0.f;
  __syncthreads();
  float acc = 0.f;
  const f16* xp = Xc + (size_t)(b * TT + tbase) * DD + d;
  const int lim = (nb - tbase < 256) ? (nb - tbase) : 256;
  for (int i = 0; i < lim; ++i) acc += (float)xp[(size_t)i * DD] * wsm[i];
  atomicAdd(&out[b * DD + d], acc);
}

extern "C" void kernel_launch(void* const* d_in, const int* in_sizes, int n_in,
                              void* d_out, int out_size, void* d_ws, size_t ws_size,
                              hipStream_t stream) {
  const float* X    = (const float*)d_in[0];
  const int*   mask = (const int*)d_in[1];
  const float* Wq_w = (const float*)d_in[2];
  const float* Wq_b = (const float*)d_in[3];
  const float* Wk_w = (const float*)d_in[4];
  const float* Wk_b = (const float*)d_in[5];
  float* out = (float*)d_out;
  (void)Wk_b;   // cancels in row-softmax (u[i], c terms)

  const size_t n2 = (size_t)MM * DD;      // 25.17M f16 elems
  const size_t wde = (size_t)DD * DD;

  // workspace layout (~106 MB)
  char* p = (char*)d_ws;
  f16* Yf  = (f16*)p;           p += n2 * sizeof(f16);
  f16* Xc  = (f16*)p;           p += n2 * sizeof(f16);
  f16* WqT = (f16*)p;           p += wde * sizeof(f16);
  f16* WkT = (f16*)p;           p += wde * sizeof(f16);
  f16* MT  = (f16*)p;           p += wde * sizeof(f16);
  float* ev = (float*)p;        p += DD * sizeof(float);
  int* idx = (int*)p;           p += (size_t)MM * sizeof(int);
  int* nbv = (int*)p;           p += 64;
  float* vb = (float*)p;        p += (size_t)MM * sizeof(float);
  float* pz = (float*)p;        p += (size_t)12 * MM * sizeof(float);
  float* sdg = (float*)p;       p += (size_t)MM * sizeof(float);
  float* wdiagc = (float*)p;    p += (size_t)MM * sizeof(float);

  compact_evec<<<11, 256, 0, stream>>>(mask, idx, nbv, Wk_w, Wq_b, ev);
  prep2<<<4384, 256, 0, stream>>>(X, idx, nbv, ev, Xc, vb,
                                  Wq_w, Wk_w, WqT, WkT);
  gemm_mt<<<dim3(12, 3), 256, 0, stream>>>(WkT, WqT, MT);
  projY<<<dim3(512, 3), 256, 0, stream>>>(Xc, MT, nbv, Yf);
  attn17c<<<1536, 256, 0, stream>>>(Yf, Xc, vb, nbv, pz, sdg);
  merge12c<<<128, 256, 0, stream>>>(pz, sdg, nbv, wdiagc, out);
  out_gemv_c<<<dim3(16, 3, 8), 256, 0, stream>>>(Xc, wdiagc, nbv, out);
}